// Round 20
// baseline (256.485 us; speedup 1.0000x reference)
//
#include <hip/hip_runtime.h>
#include <math.h>

// NeuralTPP: B=4096, L=512, H=HH=32 — register-resident MFMA recurrence.
// R19 = R18 (243us) + 8-wide single-rcp recovery for r/z sigmoid groups:
//   1 v_rcp per 8 sigmoids via product-tree (safe: r/z factors <= 2^9).
//   n & intensity groups stay pairwise (S2-scaled, tree would overflow).
// Trans/step: 24 exp2 + 6 rcp (was 24+12).
// Wave A: 6 MFMA + trans chains + h-update; no VMEM, 1 barrier/16 steps.
// Wave B: p-MFMA + intensity tail on previous chunk's h ring; hidden.

constexpr int Bn = 4096;
constexpr int Ln = 512;
constexpr float EPSf = 1e-8f;
constexpr float LOG2E  = 1.44269504088896f;
constexpr float S2     = 2.0f * LOG2E;        // tanh scale

typedef _Float16 f16x8 __attribute__((ext_vector_type(8)));
typedef float    f32x4 __attribute__((ext_vector_type(4)));

__device__ __forceinline__ float aexp2(float x) {   // v_exp_f32 = 2^x
    float r;
    asm volatile("v_exp_f32 %0, %1" : "=v"(r) : "v"(x));
    return r;
}
__device__ __forceinline__ float arcp(float x) {    // v_rcp_f32
    float r;
    asm volatile("v_rcp_f32 %0, %1" : "=v"(r) : "v"(x));
    return r;
}
// Pairwise: sg[e] = 1/(1+ex[e]), 4 rcp per 8. Safe for any ex <= ~2^60.
__device__ __forceinline__ void sig8(const float* ex, float* sg) {
    float a[8];
#pragma unroll
    for (int e = 0; e < 8; ++e) a[e] = 1.0f + ex[e];
    float inv[4];
#pragma unroll
    for (int i = 0; i < 4; ++i) inv[i] = arcp(a[2 * i] * a[2 * i + 1]);
#pragma unroll
    for (int i = 0; i < 4; ++i) {
        sg[2 * i]     = inv[i] * a[2 * i + 1];
        sg[2 * i + 1] = inv[i] * a[2 * i];
    }
}
// 8-wide: sg[e] = 1/(1+ex[e]) with ONE rcp (product tree + recovery).
// REQUIRES factors (1+ex) <= ~2^13 each (product < 2^127): true for the
// r/z groups (LOG2E-scaled pre-acts, |pre_r|,|pre_z| <= ~9 -> ex <= 2^9).
__device__ __forceinline__ void sig8w(const float* ex, float* sg) {
    float a[8];
#pragma unroll
    for (int e = 0; e < 8; ++e) a[e] = 1.0f + ex[e];
    const float t01 = a[0] * a[1], t23 = a[2] * a[3];
    const float t45 = a[4] * a[5], t67 = a[6] * a[7];
    const float t03 = t01 * t23, t47 = t45 * t67;
    const float inv07 = arcp(t03 * t47);
    const float i03 = inv07 * t47, i47 = inv07 * t03;
    const float i01 = i03 * t23, i23 = i03 * t01;
    const float i45 = i47 * t67, i67 = i47 * t45;
    sg[0] = i01 * a[1]; sg[1] = i01 * a[0];
    sg[2] = i23 * a[3]; sg[3] = i23 * a[2];
    sg[4] = i45 * a[5]; sg[5] = i45 * a[4];
    sg[6] = i67 * a[7]; sg[7] = i67 * a[6];
}

__device__ __forceinline__ float softplusf_(float x) {
    return fmaxf(x, 0.0f) + __logf(1.0f + __expf(-fabsf(x)));
}
__device__ __forceinline__ float sigmoidf_(float x) {
    return __fdividef(1.0f, 1.0f + __expf(-x));
}

union PK2 { _Float16 f[2]; unsigned u; };

__global__ __launch_bounds__(128, 1)
void tpp_main(const float* __restrict__ deltas,
              const float* __restrict__ mask,
              const float* __restrict__ w_ih,
              const float* __restrict__ w_hh,
              const float* __restrict__ b_ih,
              const float* __restrict__ b_hh,
              const float* __restrict__ w1,
              const float* __restrict__ b1,
              const float* __restrict__ w2,
              const float* __restrict__ b2,
              float* __restrict__ partials)   // [2 * gridDim.x]
{
    const int tid = threadIdx.x;
    const int w   = tid >> 6;            // 0 = recurrence wave A, 1 = tail wave B
    const int l   = tid & 63;
    const int c   = l & 15;              // batch column / A-tile row
    const int g   = l >> 4;              // k-group & C row-group
    const int b0  = blockIdx.x * 16;

    __shared__ float2   tm[16][514];                 // (tau,mask)    65.8 KB
    __shared__ unsigned ibuf[16 * 520];              // (raw,v2)      33.3 KB
    __shared__ f16x8    bfbuf[2][16][16][5];         // h ring (pad5) 40 KB

    // ---- stage (tau, mask) into LDS; zero the 2-col pad ----
    for (int q = tid; q < 16 * 128; q += 128) {
        const int cc = q >> 7;
        const int t4 = (q & 127) << 2;
        const float4 dv = *(const float4*)(deltas + (size_t)(b0 + cc) * Ln + t4);
        const float4 mv = *(const float4*)(mask   + (size_t)(b0 + cc) * Ln + t4);
        tm[cc][t4 + 0] = make_float2(dv.x, mv.x);
        tm[cc][t4 + 1] = make_float2(dv.y, mv.y);
        tm[cc][t4 + 2] = make_float2(dv.z, mv.z);
        tm[cc][t4 + 3] = make_float2(dv.w, mv.w);
    }
    if (tid < 32) tm[tid & 15][512 + (tid >> 4)] = make_float2(0.0f, 0.0f);

    // ---- per-wave constants ----
    f16x8 Af[6];                                   // A: r0,r1,n0,n1,z0,z1
    float wrAn[8], wrBn[8], wzAn[8], wzBn[8];      // r/z: NEGATED x LOG2E
    float wnA[8], wnB[8];                          // n: x S2
    f32x4 Cn0 = {}, Cn1 = {};                      // n C-init (S2*bhh_n), const
    float hreg[8];
    f16x8 Afp[2];                                  // B: p0,p1 tiles (x S2)
    float wpA[8], wpB[8];                          // B: p C-init scalars
    float w2v[8], civ[8], civs = 0.0f, b2v = 0.0f; // B scalars

    const int ub = 8 * (c >> 2) + (c & 3);
    const int j0 = 8 * g;
    if (w == 0) {
        // tile order: 0,1 = r ; 2,3 = n ; 4,5 = z
#pragma unroll
        for (int T = 0; T < 6; ++T) {
            const int G = T >> 1, p = T & 1;       // G: 0=r 1=n 2=z
            const int up = ub + 4 * p;
            const float sc = (G == 1) ? S2 : -LOG2E;
            const float* src =
                (G == 0) ? (w_hh + (size_t)up * 32 + j0) :
                (G == 1) ? (w_hh + (size_t)(64 + up) * 32 + j0) :
                           (w_hh + (size_t)(32 + up) * 32 + j0);
#pragma unroll
            for (int e = 0; e < 8; ++e) Af[T][e] = (_Float16)(src[e] * sc);
        }
#pragma unroll
        for (int e = 0; e < 8; ++e) {
            const int u = 8 * g + e;
            wrAn[e] = -w_ih[u] * LOG2E;
            wrBn[e] = -(b_ih[u] + b_hh[u]) * LOG2E;
            wzAn[e] = -w_ih[32 + u] * LOG2E;
            wzBn[e] = -(b_ih[32 + u] + b_hh[32 + u]) * LOG2E;
            wnA[e]  = w_ih[64 + u] * S2;
            wnB[e]  = b_ih[64 + u] * S2;
            hreg[e] = 0.0f;
        }
#pragma unroll
        for (int d = 0; d < 4; ++d) {
            Cn0[d] = b_hh[64 + 8 * g + d] * S2;
            Cn1[d] = b_hh[64 + 8 * g + 4 + d] * S2;
        }
    } else {
#pragma unroll
        for (int p = 0; p < 2; ++p) {
            const int up = ub + 4 * p;
            const float* src = w1 + (size_t)up * 33 + 1 + j0;
#pragma unroll
            for (int e = 0; e < 8; ++e) Afp[p][e] = (_Float16)(src[e] * S2);
        }
#pragma unroll
        for (int e = 0; e < 8; ++e) {
            const int u = 8 * g + e;
            wpA[e] = w1[(size_t)u * 33] * S2;
            wpB[e] = b1[u] * S2;
            w2v[e] = w2[u];
            civ[e] = w1[(size_t)u * 33] * w2v[e];
            civs  += civ[e];
        }
        b2v = b2[0];
    }

    __syncthreads();

    constexpr int NC = Ln / 16;          // 32 chunks

    // ---- loop-carried state for wave A: current step's C operands ----
    f32x4 Cr0, Cr1, Cz0, Cz1;
    float nbase[8];
    float mcur = 0.0f;
    if (w == 0) {
        const float2 t0v = tm[c][0];
        mcur = t0v.y;
#pragma unroll
        for (int d = 0; d < 4; ++d) {
            Cr0[d] = fmaf(t0v.x, wrAn[d],     wrBn[d]);
            Cr1[d] = fmaf(t0v.x, wrAn[4 + d], wrBn[4 + d]);
            Cz0[d] = fmaf(t0v.x, wzAn[d],     wzBn[d]);
            Cz1[d] = fmaf(t0v.x, wzAn[4 + d], wzBn[4 + d]);
        }
#pragma unroll
        for (int e = 0; e < 8; ++e) nbase[e] = fmaf(t0v.x, wnA[e], wnB[e]);
    }

    for (int chunk = 0; chunk <= NC; ++chunk) {
        if (w == 0 && chunk < NC) {
            const int tbase = chunk * 16;
            for (int s = 0; s < 16; ++s) {
                const int t = tbase + s;

                // ---- pack h -> f16 B-fragment (cvt_pkrtz) ----
                f16x8 bf;
#pragma unroll
                for (int e2 = 0; e2 < 4; ++e2) {
                    const auto pp = __builtin_amdgcn_cvt_pkrtz(hreg[2 * e2], hreg[2 * e2 + 1]);
                    bf[2 * e2]     = (_Float16)pp[0];
                    bf[2 * e2 + 1] = (_Float16)pp[1];
                }
                bfbuf[chunk & 1][s][c][g] = bf;     // for wave B (fire-and-forget)

                // ---- 6 MFMAs: r first (gates n), z last ----
                f32x4 ar0 = __builtin_amdgcn_mfma_f32_16x16x32_f16(Af[0], bf, Cr0, 0, 0, 0);
                f32x4 ar1 = __builtin_amdgcn_mfma_f32_16x16x32_f16(Af[1], bf, Cr1, 0, 0, 0);
                f32x4 an0 = __builtin_amdgcn_mfma_f32_16x16x32_f16(Af[2], bf, Cn0, 0, 0, 0);
                f32x4 an1 = __builtin_amdgcn_mfma_f32_16x16x32_f16(Af[3], bf, Cn1, 0, 0, 0);
                f32x4 az0 = __builtin_amdgcn_mfma_f32_16x16x32_f16(Af[4], bf, Cz0, 0, 0, 0);
                f32x4 az1 = __builtin_amdgcn_mfma_f32_16x16x32_f16(Af[5], bf, Cz1, 0, 0, 0);

                // ---- MFMA-latency shadow: next step's C operands + nbase ----
                const float2 tmn = tm[c][t + 1];    // padded, no select
                f32x4 Nr0, Nr1, Nz0, Nz1;
                float nbn[8];
#pragma unroll
                for (int d = 0; d < 4; ++d) {
                    Nr0[d] = fmaf(tmn.x, wrAn[d],     wrBn[d]);
                    Nr1[d] = fmaf(tmn.x, wrAn[4 + d], wrBn[4 + d]);
                    Nz0[d] = fmaf(tmn.x, wzAn[d],     wzBn[d]);
                    Nz1[d] = fmaf(tmn.x, wzAn[4 + d], wzBn[4 + d]);
                }
#pragma unroll
                for (int e = 0; e < 8; ++e) nbn[e] = fmaf(tmn.x, wnA[e], wnB[e]);

                // ---- r-chain first: 8 exp2 + 1 rcp (8-wide tree) -> rg ----
                float er[8];
#pragma unroll
                for (int d = 0; d < 4; ++d) er[d]     = aexp2(ar0[d]);
#pragma unroll
                for (int d = 0; d < 4; ++d) er[4 + d] = aexp2(ar1[d]);
                float rg[8];
                sig8w(er, rg);

                // ---- n-exps (critical path) ----
                float nex[8];
#pragma unroll
                for (int e = 0; e < 8; ++e) {
                    const float accn = (e < 4) ? an0[e] : an1[e - 4];
                    nex[e] = aexp2(fmaf(rg[e], accn, nbase[e]));
                }

                // ---- z-chain in the n-exp latency shadow (8-wide) ----
                float ez[8];
#pragma unroll
                for (int d = 0; d < 4; ++d) ez[d]     = aexp2(az0[d]);
#pragma unroll
                for (int d = 0; d < 4; ++d) ez[4 + d] = aexp2(az1[d]);
                float zg[8];
                sig8w(ez, zg);
                float qm[8];
#pragma unroll
                for (int e = 0; e < 8; ++e) qm[e] = fmaf(-zg[e], mcur, mcur);  // m*(1-z)

                // ---- n-rcp (pairwise; S2-scaled, tree would overflow) ----
                float nrc[8];
                sig8(nex, nrc);
#pragma unroll
                for (int e = 0; e < 8; ++e) {
                    const float nn = fmaf(-2.0f, nrc[e], 1.0f);
                    hreg[e] = fmaf(qm[e], nn - hreg[e], hreg[e]);
                }

                // rotate loop-carried state
                Cr0 = Nr0; Cr1 = Nr1; Cz0 = Nz0; Cz1 = Nz1;
#pragma unroll
                for (int e = 0; e < 8; ++e) nbase[e] = nbn[e];
                mcur = tmn.y;
            }
        } else if (w == 1 && chunk > 0) {
            const int tbase = (chunk - 1) * 16;
            const int rb    = (chunk - 1) & 1;
#pragma unroll 2
            for (int s = 0; s < 16; ++s) {
                const f16x8 bfv = bfbuf[rb][s][c][g];
                const float tau = tm[c][tbase + s].x;
                f32x4 Cp0, Cp1;
#pragma unroll
                for (int d = 0; d < 4; ++d) {
                    Cp0[d] = fmaf(tau, wpA[d],     wpB[d]);
                    Cp1[d] = fmaf(tau, wpA[4 + d], wpB[4 + d]);
                }
                const f32x4 a0 = __builtin_amdgcn_mfma_f32_16x16x32_f16(Afp[0], bfv, Cp0, 0, 0, 0);
                const f32x4 a1v = __builtin_amdgcn_mfma_f32_16x16x32_f16(Afp[1], bfv, Cp1, 0, 0, 0);
                float aex[8];
#pragma unroll
                for (int e = 0; e < 8; ++e) aex[e] = aexp2((e < 4) ? a0[e] : a1v[e - 4]);
                float arc[8];
                sig8(aex, arc);
                float v1p = 0.0f, v2p = civs;
#pragma unroll
                for (int e = 0; e < 8; ++e) {
                    const float a = fmaf(-2.0f, arc[e], 1.0f);
                    v1p = fmaf(a, w2v[e], v1p);
                    v2p = fmaf(a * a, -civ[e], v2p);
                }
                v1p += __shfl_xor(v1p, 16, 64);
                v1p += __shfl_xor(v1p, 32, 64);
                v2p += __shfl_xor(v2p, 16, 64);
                v2p += __shfl_xor(v2p, 32, 64);
                if (l < 16) {
                    PK2 pk;
                    pk.f[0] = (_Float16)(v1p + b2v);
                    pk.f[1] = (_Float16)v2p;
                    ibuf[l * 520 + tbase + s] = pk.u;
                }
            }
        }
        __syncthreads();
    }

    // ---- phase 2: LL transcendentals over 16 x 512 items, 128 threads ----
    float T = 0.0f, M = 0.0f;
#pragma unroll 4
    for (int it = 0; it < 64; ++it) {
        const int idx = it * 128 + tid;         // cc*512 + tt
        const int cc  = idx >> 9;
        const int tt  = idx & 511;
        PK2 pk; pk.u = ibuf[cc * 520 + tt];
        const float raw = (float)pk.f[0];
        const float v2  = (float)pk.f[1];
        const float mm  = tm[cc][tt].y;
        const float phi  = softplusf_(raw);
        const float dphi = sigmoidf_(raw) * v2;
        const float lam  = softplusf_(dphi) + EPSf;
        T = fmaf(__logf(lam) - phi, mm, T);
        M += mm;
    }
#pragma unroll
    for (int d = 1; d < 64; d <<= 1) {
        T += __shfl_xor(T, d, 64);
        M += __shfl_xor(M, d, 64);
    }
    __shared__ float sT[2], sM[2];
    if (l == 0) { sT[w] = T; sM[w] = M; }
    __syncthreads();
    if (tid == 0) {
        partials[blockIdx.x]             = sT[0] + sT[1];
        partials[gridDim.x + blockIdx.x] = sM[0] + sM[1];
    }
}

__global__ __launch_bounds__(256)
void tpp_final(const float* __restrict__ partials, int nparts,
               float* __restrict__ out)
{
    const int tid = threadIdx.x;
    double T = 0.0, M = 0.0;
    for (int k = tid; k < nparts; k += 256) {
        T += (double)partials[k];
        M += (double)partials[nparts + k];
    }
#pragma unroll
    for (int d = 1; d < 64; d <<= 1) {
        T += __shfl_xor(T, d, 64);
        M += __shfl_xor(M, d, 64);
    }
    __shared__ double sT[4], sM[4];
    const int w = tid >> 6;
    if ((tid & 63) == 0) { sT[w] = T; sM[w] = M; }
    __syncthreads();
    if (tid == 0) {
        const double t2 = sT[0] + sT[1] + sT[2] + sT[3];
        const double m2 = sM[0] + sM[1] + sM[2] + sM[3];
        out[0] = (float)(t2 / (m2 + (double)EPSf));
    }
}

extern "C" void kernel_launch(void* const* d_in, const int* in_sizes, int n_in,
                              void* d_out, int out_size, void* d_ws, size_t ws_size,
                              hipStream_t stream) {
    const float* deltas = (const float*)d_in[0];
    const float* mask   = (const float*)d_in[1];
    const float* w_ih   = (const float*)d_in[2];
    const float* w_hh   = (const float*)d_in[3];
    const float* b_ih   = (const float*)d_in[4];
    const float* b_hh   = (const float*)d_in[5];
    const float* w1     = (const float*)d_in[6];
    const float* b1     = (const float*)d_in[7];
    const float* w2     = (const float*)d_in[8];
    const float* b2     = (const float*)d_in[9];
    float* out = (float*)d_out;
    float* partials = (float*)d_ws;      // 2 * 256 * 4 B

    const int nblocks = Bn / 16;         // 256
    tpp_main<<<nblocks, 128, 0, stream>>>(deltas, mask, w_ih, w_hh, b_ih, b_hh,
                                          w1, b1, w2, b2, partials);
    tpp_final<<<1, 256, 0, stream>>>(partials, nblocks, out);
}

// Round 21
// 242.519 us; speedup vs baseline: 1.0576x; 1.0576x over previous
//
#include <hip/hip_runtime.h>
#include <math.h>

// NeuralTPP: B=4096, L=512, H=HH=32 — register-resident MFMA recurrence.
// FINAL (= R18, 243us): pairwise-rcp everywhere (R19's 8-wide tree added
// more dependent-chain latency than it saved in rcp issue — reverted).
//  - h lives in registers as the next step's MFMA B-fragment (R5 row
//    permutation, zero repack); 6 MFMA/step; biases folded into MFMA C.
//  - asm-forced exp2/rcp ILP (R12, the big win: compiler otherwise
//    latency-serializes the chains at ~11 cyc/instr).
//  - chain order: r-exps -> r-rcp -> n-exps with z-chain in n's shadow.
//  - zero VMEM in the recurrence loop; 1 barrier / 16 steps; intensity
//    tail + p-gate MFMA on wave B, one chunk behind (fully hidden).
// Floor evidence: trans-issue+tail ~1140 cyc/step; parallelization is
// sync-poisoned (R8/R10/R17); wave count capped at 256 by B/16.

constexpr int Bn = 4096;
constexpr int Ln = 512;
constexpr float EPSf = 1e-8f;
constexpr float LOG2E  = 1.44269504088896f;
constexpr float S2     = 2.0f * LOG2E;        // tanh scale

typedef _Float16 f16x8 __attribute__((ext_vector_type(8)));
typedef float    f32x4 __attribute__((ext_vector_type(4)));

__device__ __forceinline__ float aexp2(float x) {   // v_exp_f32 = 2^x
    float r;
    asm volatile("v_exp_f32 %0, %1" : "=v"(r) : "v"(x));
    return r;
}
__device__ __forceinline__ float arcp(float x) {    // v_rcp_f32
    float r;
    asm volatile("v_rcp_f32 %0, %1" : "=v"(r) : "v"(x));
    return r;
}
// sg[e] = 1/(1+ex[e]) for 8 values with 4 rcp (pair-product recovery).
__device__ __forceinline__ void sig8(const float* ex, float* sg) {
    float a[8];
#pragma unroll
    for (int e = 0; e < 8; ++e) a[e] = 1.0f + ex[e];
    float inv[4];
#pragma unroll
    for (int i = 0; i < 4; ++i) inv[i] = arcp(a[2 * i] * a[2 * i + 1]);
#pragma unroll
    for (int i = 0; i < 4; ++i) {
        sg[2 * i]     = inv[i] * a[2 * i + 1];
        sg[2 * i + 1] = inv[i] * a[2 * i];
    }
}

__device__ __forceinline__ float softplusf_(float x) {
    return fmaxf(x, 0.0f) + __logf(1.0f + __expf(-fabsf(x)));
}
__device__ __forceinline__ float sigmoidf_(float x) {
    return __fdividef(1.0f, 1.0f + __expf(-x));
}

union PK2 { _Float16 f[2]; unsigned u; };

__global__ __launch_bounds__(128, 1)
void tpp_main(const float* __restrict__ deltas,
              const float* __restrict__ mask,
              const float* __restrict__ w_ih,
              const float* __restrict__ w_hh,
              const float* __restrict__ b_ih,
              const float* __restrict__ b_hh,
              const float* __restrict__ w1,
              const float* __restrict__ b1,
              const float* __restrict__ w2,
              const float* __restrict__ b2,
              float* __restrict__ partials)   // [2 * gridDim.x]
{
    const int tid = threadIdx.x;
    const int w   = tid >> 6;            // 0 = recurrence wave A, 1 = tail wave B
    const int l   = tid & 63;
    const int c   = l & 15;              // batch column / A-tile row
    const int g   = l >> 4;              // k-group & C row-group
    const int b0  = blockIdx.x * 16;

    __shared__ float2   tm[16][514];                 // (tau,mask)    65.8 KB
    __shared__ unsigned ibuf[16 * 520];              // (raw,v2)      33.3 KB
    __shared__ f16x8    bfbuf[2][16][16][5];         // h ring (pad5) 40 KB

    // ---- stage (tau, mask) into LDS; zero the 2-col pad ----
    for (int q = tid; q < 16 * 128; q += 128) {
        const int cc = q >> 7;
        const int t4 = (q & 127) << 2;
        const float4 dv = *(const float4*)(deltas + (size_t)(b0 + cc) * Ln + t4);
        const float4 mv = *(const float4*)(mask   + (size_t)(b0 + cc) * Ln + t4);
        tm[cc][t4 + 0] = make_float2(dv.x, mv.x);
        tm[cc][t4 + 1] = make_float2(dv.y, mv.y);
        tm[cc][t4 + 2] = make_float2(dv.z, mv.z);
        tm[cc][t4 + 3] = make_float2(dv.w, mv.w);
    }
    if (tid < 32) tm[tid & 15][512 + (tid >> 4)] = make_float2(0.0f, 0.0f);

    // ---- per-wave constants ----
    f16x8 Af[6];                                   // A: r0,r1,n0,n1,z0,z1
    float wrAn[8], wrBn[8], wzAn[8], wzBn[8];      // r/z: NEGATED x LOG2E
    float wnA[8], wnB[8];                          // n: x S2
    f32x4 Cn0 = {}, Cn1 = {};                      // n C-init (S2*bhh_n), const
    float hreg[8];
    f16x8 Afp[2];                                  // B: p0,p1 tiles (x S2)
    float wpA[8], wpB[8];                          // B: p C-init scalars
    float w2v[8], civ[8], civs = 0.0f, b2v = 0.0f; // B scalars

    const int ub = 8 * (c >> 2) + (c & 3);
    const int j0 = 8 * g;
    if (w == 0) {
        // tile order: 0,1 = r ; 2,3 = n ; 4,5 = z
#pragma unroll
        for (int T = 0; T < 6; ++T) {
            const int G = T >> 1, p = T & 1;       // G: 0=r 1=n 2=z
            const int up = ub + 4 * p;
            const float sc = (G == 1) ? S2 : -LOG2E;
            const float* src =
                (G == 0) ? (w_hh + (size_t)up * 32 + j0) :
                (G == 1) ? (w_hh + (size_t)(64 + up) * 32 + j0) :
                           (w_hh + (size_t)(32 + up) * 32 + j0);
#pragma unroll
            for (int e = 0; e < 8; ++e) Af[T][e] = (_Float16)(src[e] * sc);
        }
#pragma unroll
        for (int e = 0; e < 8; ++e) {
            const int u = 8 * g + e;
            wrAn[e] = -w_ih[u] * LOG2E;
            wrBn[e] = -(b_ih[u] + b_hh[u]) * LOG2E;
            wzAn[e] = -w_ih[32 + u] * LOG2E;
            wzBn[e] = -(b_ih[32 + u] + b_hh[32 + u]) * LOG2E;
            wnA[e]  = w_ih[64 + u] * S2;
            wnB[e]  = b_ih[64 + u] * S2;
            hreg[e] = 0.0f;
        }
#pragma unroll
        for (int d = 0; d < 4; ++d) {
            Cn0[d] = b_hh[64 + 8 * g + d] * S2;
            Cn1[d] = b_hh[64 + 8 * g + 4 + d] * S2;
        }
    } else {
#pragma unroll
        for (int p = 0; p < 2; ++p) {
            const int up = ub + 4 * p;
            const float* src = w1 + (size_t)up * 33 + 1 + j0;
#pragma unroll
            for (int e = 0; e < 8; ++e) Afp[p][e] = (_Float16)(src[e] * S2);
        }
#pragma unroll
        for (int e = 0; e < 8; ++e) {
            const int u = 8 * g + e;
            wpA[e] = w1[(size_t)u * 33] * S2;
            wpB[e] = b1[u] * S2;
            w2v[e] = w2[u];
            civ[e] = w1[(size_t)u * 33] * w2v[e];
            civs  += civ[e];
        }
        b2v = b2[0];
    }

    __syncthreads();

    constexpr int NC = Ln / 16;          // 32 chunks

    // ---- loop-carried state for wave A: current step's C operands ----
    f32x4 Cr0, Cr1, Cz0, Cz1;
    float nbase[8];
    float mcur = 0.0f;
    if (w == 0) {
        const float2 t0v = tm[c][0];
        mcur = t0v.y;
#pragma unroll
        for (int d = 0; d < 4; ++d) {
            Cr0[d] = fmaf(t0v.x, wrAn[d],     wrBn[d]);
            Cr1[d] = fmaf(t0v.x, wrAn[4 + d], wrBn[4 + d]);
            Cz0[d] = fmaf(t0v.x, wzAn[d],     wzBn[d]);
            Cz1[d] = fmaf(t0v.x, wzAn[4 + d], wzBn[4 + d]);
        }
#pragma unroll
        for (int e = 0; e < 8; ++e) nbase[e] = fmaf(t0v.x, wnA[e], wnB[e]);
    }

    for (int chunk = 0; chunk <= NC; ++chunk) {
        if (w == 0 && chunk < NC) {
            const int tbase = chunk * 16;
            for (int s = 0; s < 16; ++s) {
                const int t = tbase + s;

                // ---- pack h -> f16 B-fragment (cvt_pkrtz) ----
                f16x8 bf;
#pragma unroll
                for (int e2 = 0; e2 < 4; ++e2) {
                    const auto pp = __builtin_amdgcn_cvt_pkrtz(hreg[2 * e2], hreg[2 * e2 + 1]);
                    bf[2 * e2]     = (_Float16)pp[0];
                    bf[2 * e2 + 1] = (_Float16)pp[1];
                }
                bfbuf[chunk & 1][s][c][g] = bf;     // for wave B (fire-and-forget)

                // ---- 6 MFMAs: r first (gates n), z last ----
                f32x4 ar0 = __builtin_amdgcn_mfma_f32_16x16x32_f16(Af[0], bf, Cr0, 0, 0, 0);
                f32x4 ar1 = __builtin_amdgcn_mfma_f32_16x16x32_f16(Af[1], bf, Cr1, 0, 0, 0);
                f32x4 an0 = __builtin_amdgcn_mfma_f32_16x16x32_f16(Af[2], bf, Cn0, 0, 0, 0);
                f32x4 an1 = __builtin_amdgcn_mfma_f32_16x16x32_f16(Af[3], bf, Cn1, 0, 0, 0);
                f32x4 az0 = __builtin_amdgcn_mfma_f32_16x16x32_f16(Af[4], bf, Cz0, 0, 0, 0);
                f32x4 az1 = __builtin_amdgcn_mfma_f32_16x16x32_f16(Af[5], bf, Cz1, 0, 0, 0);

                // ---- MFMA-latency shadow: next step's C operands + nbase ----
                const float2 tmn = tm[c][t + 1];    // padded, no select
                f32x4 Nr0, Nr1, Nz0, Nz1;
                float nbn[8];
#pragma unroll
                for (int d = 0; d < 4; ++d) {
                    Nr0[d] = fmaf(tmn.x, wrAn[d],     wrBn[d]);
                    Nr1[d] = fmaf(tmn.x, wrAn[4 + d], wrBn[4 + d]);
                    Nz0[d] = fmaf(tmn.x, wzAn[d],     wzBn[d]);
                    Nz1[d] = fmaf(tmn.x, wzAn[4 + d], wzBn[4 + d]);
                }
#pragma unroll
                for (int e = 0; e < 8; ++e) nbn[e] = fmaf(tmn.x, wnA[e], wnB[e]);

                // ---- r-chain first: 8 exp2 + 4 rcp -> rg ----
                float er[8];
#pragma unroll
                for (int d = 0; d < 4; ++d) er[d]     = aexp2(ar0[d]);
#pragma unroll
                for (int d = 0; d < 4; ++d) er[4 + d] = aexp2(ar1[d]);
                float rg[8];
                sig8(er, rg);

                // ---- n-exps (critical path) ----
                float nex[8];
#pragma unroll
                for (int e = 0; e < 8; ++e) {
                    const float accn = (e < 4) ? an0[e] : an1[e - 4];
                    nex[e] = aexp2(fmaf(rg[e], accn, nbase[e]));
                }

                // ---- z-chain in the n-exp latency shadow ----
                float ez[8];
#pragma unroll
                for (int d = 0; d < 4; ++d) ez[d]     = aexp2(az0[d]);
#pragma unroll
                for (int d = 0; d < 4; ++d) ez[4 + d] = aexp2(az1[d]);
                float zg[8];
                sig8(ez, zg);
                float qm[8];
#pragma unroll
                for (int e = 0; e < 8; ++e) qm[e] = fmaf(-zg[e], mcur, mcur);  // m*(1-z)

                // ---- n-rcp (paired) + h update ----
                float nrc[8];
                sig8(nex, nrc);
#pragma unroll
                for (int e = 0; e < 8; ++e) {
                    const float nn = fmaf(-2.0f, nrc[e], 1.0f);
                    hreg[e] = fmaf(qm[e], nn - hreg[e], hreg[e]);
                }

                // rotate loop-carried state
                Cr0 = Nr0; Cr1 = Nr1; Cz0 = Nz0; Cz1 = Nz1;
#pragma unroll
                for (int e = 0; e < 8; ++e) nbase[e] = nbn[e];
                mcur = tmn.y;
            }
        } else if (w == 1 && chunk > 0) {
            const int tbase = (chunk - 1) * 16;
            const int rb    = (chunk - 1) & 1;
#pragma unroll 2
            for (int s = 0; s < 16; ++s) {
                const f16x8 bfv = bfbuf[rb][s][c][g];
                const float tau = tm[c][tbase + s].x;
                f32x4 Cp0, Cp1;
#pragma unroll
                for (int d = 0; d < 4; ++d) {
                    Cp0[d] = fmaf(tau, wpA[d],     wpB[d]);
                    Cp1[d] = fmaf(tau, wpA[4 + d], wpB[4 + d]);
                }
                const f32x4 a0 = __builtin_amdgcn_mfma_f32_16x16x32_f16(Afp[0], bfv, Cp0, 0, 0, 0);
                const f32x4 a1v = __builtin_amdgcn_mfma_f32_16x16x32_f16(Afp[1], bfv, Cp1, 0, 0, 0);
                float aex[8];
#pragma unroll
                for (int e = 0; e < 8; ++e) aex[e] = aexp2((e < 4) ? a0[e] : a1v[e - 4]);
                float arc[8];
                sig8(aex, arc);
                float v1p = 0.0f, v2p = civs;
#pragma unroll
                for (int e = 0; e < 8; ++e) {
                    const float a = fmaf(-2.0f, arc[e], 1.0f);
                    v1p = fmaf(a, w2v[e], v1p);
                    v2p = fmaf(a * a, -civ[e], v2p);
                }
                v1p += __shfl_xor(v1p, 16, 64);
                v1p += __shfl_xor(v1p, 32, 64);
                v2p += __shfl_xor(v2p, 16, 64);
                v2p += __shfl_xor(v2p, 32, 64);
                if (l < 16) {
                    PK2 pk;
                    pk.f[0] = (_Float16)(v1p + b2v);
                    pk.f[1] = (_Float16)v2p;
                    ibuf[l * 520 + tbase + s] = pk.u;
                }
            }
        }
        __syncthreads();
    }

    // ---- phase 2: LL transcendentals over 16 x 512 items, 128 threads ----
    float T = 0.0f, M = 0.0f;
#pragma unroll 4
    for (int it = 0; it < 64; ++it) {
        const int idx = it * 128 + tid;         // cc*512 + tt
        const int cc  = idx >> 9;
        const int tt  = idx & 511;
        PK2 pk; pk.u = ibuf[cc * 520 + tt];
        const float raw = (float)pk.f[0];
        const float v2  = (float)pk.f[1];
        const float mm  = tm[cc][tt].y;
        const float phi  = softplusf_(raw);
        const float dphi = sigmoidf_(raw) * v2;
        const float lam  = softplusf_(dphi) + EPSf;
        T = fmaf(__logf(lam) - phi, mm, T);
        M += mm;
    }
#pragma unroll
    for (int d = 1; d < 64; d <<= 1) {
        T += __shfl_xor(T, d, 64);
        M += __shfl_xor(M, d, 64);
    }
    __shared__ float sT[2], sM[2];
    if (l == 0) { sT[w] = T; sM[w] = M; }
    __syncthreads();
    if (tid == 0) {
        partials[blockIdx.x]             = sT[0] + sT[1];
        partials[gridDim.x + blockIdx.x] = sM[0] + sM[1];
    }
}

__global__ __launch_bounds__(256)
void tpp_final(const float* __restrict__ partials, int nparts,
               float* __restrict__ out)
{
    const int tid = threadIdx.x;
    double T = 0.0, M = 0.0;
    for (int k = tid; k < nparts; k += 256) {
        T += (double)partials[k];
        M += (double)partials[nparts + k];
    }
#pragma unroll
    for (int d = 1; d < 64; d <<= 1) {
        T += __shfl_xor(T, d, 64);
        M += __shfl_xor(M, d, 64);
    }
    __shared__ double sT[4], sM[4];
    const int w = tid >> 6;
    if ((tid & 63) == 0) { sT[w] = T; sM[w] = M; }
    __syncthreads();
    if (tid == 0) {
        const double t2 = sT[0] + sT[1] + sT[2] + sT[3];
        const double m2 = sM[0] + sM[1] + sM[2] + sM[3];
        out[0] = (float)(t2 / (m2 + (double)EPSf));
    }
}

extern "C" void kernel_launch(void* const* d_in, const int* in_sizes, int n_in,
                              void* d_out, int out_size, void* d_ws, size_t ws_size,
                              hipStream_t stream) {
    const float* deltas = (const float*)d_in[0];
    const float* mask   = (const float*)d_in[1];
    const float* w_ih   = (const float*)d_in[2];
    const float* w_hh   = (const float*)d_in[3];
    const float* b_ih   = (const float*)d_in[4];
    const float* b_hh   = (const float*)d_in[5];
    const float* w1     = (const float*)d_in[6];
    const float* b1     = (const float*)d_in[7];
    const float* w2     = (const float*)d_in[8];
    const float* b2     = (const float*)d_in[9];
    float* out = (float*)d_out;
    float* partials = (float*)d_ws;      // 2 * 256 * 4 B

    const int nblocks = Bn / 16;         // 256
    tpp_main<<<nblocks, 128, 0, stream>>>(deltas, mask, w_ih, w_hh, b_ih, b_hh,
                                          w1, b1, w2, b2, partials);
    tpp_final<<<1, 256, 0, stream>>>(partials, nblocks, out);
}